// Round 7
// baseline (207.142 us; speedup 1.0000x reference)
//
#include <hip/hip_runtime.h>
#include <hip/hip_bf16.h>

#define DD   4096   // hidden dim
#define NE   8      // experts
#define NR   16     // lora rank
#define NTOK 8192   // B*S
#define NDO  4096   // output dim
#define TAU  1e-4f  // ambiguity margin for the f32 routing pass
#define MAXFLAG 8000
// SCALING = 16/16 = 1.0

typedef __attribute__((ext_vector_type(8))) __bf16 bf16x8;
typedef __attribute__((ext_vector_type(4))) float  f32x4;

__device__ __forceinline__ bf16x8 to_bf16x8(float4 a, float4 b) {
    bf16x8 r;
    r[0] = (__bf16)a.x; r[1] = (__bf16)a.y; r[2] = (__bf16)a.z; r[3] = (__bf16)a.w;
    r[4] = (__bf16)b.x; r[5] = (__bf16)b.y; r[6] = (__bf16)b.z; r[7] = (__bf16)b.w;
    return r;
}

// ---------------- k1: routing fast pass (f32, split-D) + binning ----------------
// OCCUPANCY-FIRST: 2048 blocks x 256 thr (4 waves). Block = 4 tokens; wave wv
// covers D-slice [wv*1024, +1024). acc f32[4][8]=32 VGPR (no f64 -> no r3 spill).
// Ambiguous tokens (top-2 gap < TAU) -> flag list, exact f64 re-check in k_fix.
__global__ __launch_bounds__(256, 5) void k_route(const float* __restrict__ x,
                                                  const float* __restrict__ rw,
                                                  float* __restrict__ w_arr,
                                                  int*   __restrict__ token_list,
                                                  int*   __restrict__ count,
                                                  int*   __restrict__ nflag,
                                                  int*   __restrict__ flaglist) {
    const int wv   = threadIdx.x >> 6;
    const int lane = threadIdx.x & 63;
    const int t0   = blockIdx.x * 4;
    const float* xp = x + (size_t)t0 * DD;
    const int dbase = wv * 1024;

    float acc[4][NE];
    #pragma unroll
    for (int t = 0; t < 4; t++)
        #pragma unroll
        for (int e = 0; e < NE; e++) acc[t][e] = 0.f;

    #pragma unroll
    for (int i = 0; i < 4; i++) {
        const int d4 = dbase + (i * 64 + lane) * 4;
        float4 xv[4];
        #pragma unroll
        for (int t = 0; t < 4; t++) xv[t] = *(const float4*)(xp + (size_t)t * DD + d4);
        #pragma unroll
        for (int e = 0; e < NE; e++) {
            const float4 wv4 = *(const float4*)(rw + (size_t)e * DD + d4);
            #pragma unroll
            for (int t = 0; t < 4; t++) {
                acc[t][e] = fmaf(xv[t].x, wv4.x, acc[t][e]);
                acc[t][e] = fmaf(xv[t].y, wv4.y, acc[t][e]);
                acc[t][e] = fmaf(xv[t].z, wv4.z, acc[t][e]);
                acc[t][e] = fmaf(xv[t].w, wv4.w, acc[t][e]);
            }
        }
    }

    // 64-lane butterfly: lane 0 of each wave ends with the slice sums
    #pragma unroll
    for (int off = 32; off > 0; off >>= 1) {
        #pragma unroll
        for (int t = 0; t < 4; t++)
            #pragma unroll
            for (int e = 0; e < NE; e++)
                acc[t][e] += __shfl_xor(acc[t][e], off, 64);
    }

    // combine the 4 D-slices in LDS (statically-indexed writes from lane 0)
    __shared__ float red[4][4][NE];
    if (lane == 0) {
        #pragma unroll
        for (int t = 0; t < 4; t++)
            #pragma unroll
            for (int e = 0; e < NE; e++)
                red[wv][t][e] = acc[t][e];
    }
    __syncthreads();

    if (threadIdx.x < 4) {
        const int t = threadIdx.x;
        float best = -1e30f, second = -1e30f; int be = 0;
        #pragma unroll
        for (int e = 0; e < NE; e++) {
            const float s = red[0][t][e] + red[1][t][e] + red[2][t][e] + red[3][t][e];
            if (s > best) { second = best; best = s; be = e; }
            else if (s > second) { second = s; }
        }
        const int tok = t0 + t;
        w_arr[tok] = best;
        if (best - second < TAU) {
            const int p = atomicAdd(nflag, 1);
            if (p < MAXFLAG) flaglist[p] = tok;
        } else {
            const int p = atomicAdd(&count[be], 1);
            token_list[be * NTOK + p] = tok;
        }
    }
}

// ---------------- k1b: exact f64 re-route for ambiguous tokens ----------------
__global__ __launch_bounds__(256) void k_fix(const float* __restrict__ x,
                                             const float* __restrict__ rw,
                                             float* __restrict__ w_arr,
                                             int*   __restrict__ token_list,
                                             int*   __restrict__ count,
                                             const int* __restrict__ nflag,
                                             const int* __restrict__ flaglist) {
    const int wv   = threadIdx.x >> 6;
    const int lane = threadIdx.x & 63;
    int n = *nflag; if (n > MAXFLAG) n = MAXFLAG;

    for (int idx = wv; idx < n; idx += 4) {
        const int tok = flaglist[idx];
        const float* xp = x + (size_t)tok * DD;
        double acc[NE];
        #pragma unroll
        for (int e = 0; e < NE; e++) acc[e] = 0.0;
        for (int i = 0; i < 16; i++) {
            const int d4 = (i * 64 + lane) * 4;
            const float4 xv = *(const float4*)(xp + d4);
            const double x0 = xv.x, x1 = xv.y, x2 = xv.z, x3 = xv.w;
            #pragma unroll
            for (int e = 0; e < NE; e++) {
                const float4 wv4 = *(const float4*)(rw + (size_t)e * DD + d4);
                acc[e] = fma(x0, (double)wv4.x, acc[e]);
                acc[e] = fma(x1, (double)wv4.y, acc[e]);
                acc[e] = fma(x2, (double)wv4.z, acc[e]);
                acc[e] = fma(x3, (double)wv4.w, acc[e]);
            }
        }
        #pragma unroll
        for (int off = 32; off > 0; off >>= 1)
            #pragma unroll
            for (int e = 0; e < NE; e++)
                acc[e] += __shfl_xor(acc[e], off, 64);
        if (lane == 0) {
            double best = acc[0]; int be = 0;
            #pragma unroll
            for (int e = 1; e < NE; e++) if (acc[e] > best) { best = acc[e]; be = e; }
            w_arr[tok] = (float)best;
            const int pos = atomicAdd(&count[be], 1);
            token_list[be * NTOK + pos] = tok;
        }
    }
}

// ---------------- k2: wh[tok][r] = w * (x . A[e]^T)  (bf16 out) ----------------
// r6 version (measured ~18us): 32-token tile, 16 waves, wave = K-slice 256,
// 2 token-subtiles share one A B-frag. Slots widened 64->128 for safety.
__global__ __launch_bounds__(1024) void k_h(const float* __restrict__ x,
                                            const float* __restrict__ Am,
                                            const float* __restrict__ w_arr,
                                            const int*   __restrict__ token_list,
                                            const int*   __restrict__ count,
                                            __hip_bfloat16* __restrict__ wh) {
    const int e    = blockIdx.x >> 7;         // 8 experts x 128 slots (cap 4096 tok/e)
    const int g    = blockIdx.x & 127;
    const int cnt  = count[e];
    const int base = g * 32;
    if (base >= cnt) return;

    const int wv   = threadIdx.x >> 6;        // 0..15
    const int lane = threadIdx.x & 63;
    const int m    = lane & 15;
    const int half = lane >> 4;

    const int i0 = base + m,  i1 = base + 16 + m;
    const int tok0 = (i0 < cnt) ? token_list[e * NTOK + i0] : 0;
    const int tok1 = (i1 < cnt) ? token_list[e * NTOK + i1] : 0;
    const float* xr0  = x + (size_t)tok0 * DD;
    const float* xr1  = x + (size_t)tok1 * DD;
    const float* arow = Am + ((size_t)e * NR + m) * DD;   // B-frag row r = lane&15

    f32x4 acc0 = {0.f,0.f,0.f,0.f}, acc1 = {0.f,0.f,0.f,0.f};
    const int kbase = wv * 256;
    #pragma unroll
    for (int kc = 0; kc < 8; kc++) {
        const int k0 = kbase + kc * 32 + half * 8;
        const bf16x8 bfrag = to_bf16x8(*(const float4*)(arow + k0),
                                       *(const float4*)(arow + k0 + 4));
        const bf16x8 a0 = to_bf16x8(*(const float4*)(xr0 + k0),
                                    *(const float4*)(xr0 + k0 + 4));
        const bf16x8 a1 = to_bf16x8(*(const float4*)(xr1 + k0),
                                    *(const float4*)(xr1 + k0 + 4));
        acc0 = __builtin_amdgcn_mfma_f32_16x16x32_bf16(a0, bfrag, acc0, 0, 0, 0);
        acc1 = __builtin_amdgcn_mfma_f32_16x16x32_bf16(a1, bfrag, acc1, 0, 0, 0);
    }

    // C layout: row = (lane>>4)*4 + reg (token-in-subtile), col = lane&15 (r)
    __shared__ float lds[16][32][17];
    #pragma unroll
    for (int rr = 0; rr < 4; rr++) {
        lds[wv][half * 4 + rr][m]      = acc0[rr];
        lds[wv][16 + half * 4 + rr][m] = acc1[rr];
    }
    __syncthreads();

    if (threadIdx.x < 512) {
        const int t = threadIdx.x >> 4;       // 0..31
        const int r = threadIdx.x & 15;
        const int i2 = base + t;
        if (i2 < cnt) {
            float s = 0.f;
            #pragma unroll
            for (int w = 0; w < 16; w++) s += lds[w][t][r];
            const int tk = token_list[e * NTOK + i2];
            wh[(size_t)tk * NR + r] = (__hip_bfloat16)(s * w_arr[tk]);
        }
    }
}

// ---------------- k3: out = wh . Bw[e]^T ----------------
// Occupancy-max: grid 8e x 512slots x 8chunks = 32768 blocks of 256 thr
// (4 waves). Block = 16 tokens x 512 outputs; wave = 128 outputs (8 o-tiles).
__global__ __launch_bounds__(256) void k_out(const float* __restrict__ Bw,
                                             const __hip_bfloat16* __restrict__ wh,
                                             const int*   __restrict__ token_list,
                                             const int*   __restrict__ count,
                                             float* __restrict__ out) {
    const int bx    = blockIdx.x;
    const int chunk = bx & 7;
    const int slot  = (bx >> 3) & 511;
    const int e     = bx >> 12;
    const int cnt   = count[e];
    const int base  = slot * 16;
    if (base >= cnt) return;

    const int wv   = threadIdx.x >> 6;        // 0..3
    const int lane = threadIdx.x & 63;
    const int m    = lane & 15;
    const int half = lane >> 4;

    const int  idx   = base + m;
    const bool valid = idx < cnt;
    const int  tok   = valid ? token_list[e * NTOK + idx] : 0;

    // a2 frag: wh[token m][k], k = half*8+j for half<2, zero-padded K=32
    bf16x8 a2;
    if (half < 2 && valid) {
        a2 = *(const bf16x8*)(wh + (size_t)tok * NR + half * 8);
    } else {
        #pragma unroll
        for (int j = 0; j < 8; j++) a2[j] = (__bf16)0.0f;
    }

    int trow[4]; bool vrow[4];
    #pragma unroll
    for (int r = 0; r < 4; r++) {
        const int ir = base + half * 4 + r;
        vrow[r] = ir < cnt;
        trow[r] = vrow[r] ? token_list[e * NTOK + ir] : 0;
    }

    const float* bwe = Bw + (size_t)e * NDO * NR;
    const int h2 = (half < 2) ? half : 0;
    const f32x4 zero4 = {0.f, 0.f, 0.f, 0.f};
    const int ob0 = chunk * 512 + wv * 128;

    #pragma unroll 4
    for (int ot = 0; ot < 8; ot++) {
        const int obase = ob0 + ot * 16;
        const float* bp = bwe + (size_t)(obase + m) * NR + h2 * 8;
        const float4 p = *(const float4*)(bp);
        const float4 q = *(const float4*)(bp + 4);
        bf16x8 b2 = to_bf16x8(p, q);
        if (half >= 2) {
            #pragma unroll
            for (int j = 0; j < 8; j++) b2[j] = (__bf16)0.0f;
        }
        const f32x4 d = __builtin_amdgcn_mfma_f32_16x16x32_bf16(a2, b2, zero4, 0, 0, 0);
        #pragma unroll
        for (int r = 0; r < 4; r++) {
            if (vrow[r]) out[(size_t)trow[r] * NDO + obase + m] = d[r];
        }
    }
}

// ---------------- launcher ----------------
extern "C" void kernel_launch(void* const* d_in, const int* in_sizes, int n_in,
                              void* d_out, int out_size, void* d_ws, size_t ws_size,
                              hipStream_t stream) {
    const float* x  = (const float*)d_in[0];
    const float* rw = (const float*)d_in[1];
    const float* Am = (const float*)d_in[2];
    const float* Bw = (const float*)d_in[3];
    float* out = (float*)d_out;

    char* ws = (char*)d_ws;
    int*   count      = (int*)ws;                           // 8 ints @ 0
    int*   nflag      = (int*)(ws + 32);                    // 1 int
    float* w_arr      = (float*)(ws + 512);                 // 8192 f32 -> ends 33280
    int*   flaglist   = (int*)(ws + 33280);                 // 8064 ints -> ends 65536
    int*   token_list = (int*)(ws + 65536);                 // 8*8192 ints
    __hip_bfloat16* wh = (__hip_bfloat16*)(ws + 65536 + NE * NTOK * 4); // 8192*16 bf16

    hipMemsetAsync(ws, 0, 64, stream);                      // count + nflag
    hipLaunchKernelGGL(k_route, dim3(2048),  dim3(256),  0, stream, x, rw, w_arr, token_list, count, nflag, flaglist);
    hipLaunchKernelGGL(k_fix,   dim3(1),     dim3(256),  0, stream, x, rw, w_arr, token_list, count, nflag, flaglist);
    hipLaunchKernelGGL(k_h,     dim3(1024),  dim3(1024), 0, stream, x, Am, w_arr, token_list, count, wh);
    hipLaunchKernelGGL(k_out,   dim3(32768), dim3(256),  0, stream, Bw, wh, token_list, count, out);
}

// Round 8
// 170.638 us; speedup vs baseline: 1.2139x; 1.2139x over previous
//
#include <hip/hip_runtime.h>
#include <hip/hip_bf16.h>

#define DD   4096   // hidden dim
#define NE   8      // experts
#define NR   16     // lora rank
#define NTOK 8192   // B*S
#define NDO  4096   // output dim
#define TAU  4e-4f  // ambiguity margin for the hi/lo MFMA routing pass
#define MAXFLAG 8000
// SCALING = 16/16 = 1.0

typedef __attribute__((ext_vector_type(8))) __bf16 bf16x8;
typedef __attribute__((ext_vector_type(4))) float  f32x4;

__device__ __forceinline__ bf16x8 to_bf16x8(float4 a, float4 b) {
    bf16x8 r;
    r[0] = (__bf16)a.x; r[1] = (__bf16)a.y; r[2] = (__bf16)a.z; r[3] = (__bf16)a.w;
    r[4] = (__bf16)b.x; r[5] = (__bf16)b.y; r[6] = (__bf16)b.z; r[7] = (__bf16)b.w;
    return r;
}

// residual: lo = bf16(v - f32(hi))
__device__ __forceinline__ bf16x8 lo_bf16x8(float4 a, float4 b, bf16x8 h) {
    bf16x8 r;
    r[0] = (__bf16)(a.x - (float)h[0]); r[1] = (__bf16)(a.y - (float)h[1]);
    r[2] = (__bf16)(a.z - (float)h[2]); r[3] = (__bf16)(a.w - (float)h[3]);
    r[4] = (__bf16)(b.x - (float)h[4]); r[5] = (__bf16)(b.y - (float)h[5]);
    r[6] = (__bf16)(b.z - (float)h[6]); r[7] = (__bf16)(b.w - (float)h[7]);
    return r;
}

// ---------------- k1: routing via hi/lo bf16 MFMA (k_h-style) ----------------
// 512 blocks x 1024 thr (16 waves). Block = 16 tokens; wave = K-slice 256.
// B-frag rows 0-7 = bf16_hi(rw[e]), rows 8-15 = bf16_lo(rw[e]).
// mfma(xh,B) + mfma(xl,B) -> logit[t][e] = cols e and e+8 of both accs summed.
// Error ~2e-5; tokens with top-2 gap < TAU get exact f64 re-route in k_fix.
__global__ __launch_bounds__(1024) void k_route(const float* __restrict__ x,
                                                const float* __restrict__ rw,
                                                float* __restrict__ w_arr,
                                                int*   __restrict__ token_list,
                                                int*   __restrict__ count,
                                                int*   __restrict__ nflag,
                                                int*   __restrict__ flaglist) {
    const int t0   = blockIdx.x * 16;
    const int wv   = threadIdx.x >> 6;        // 0..15
    const int lane = threadIdx.x & 63;
    const int m    = lane & 15;               // A row (token) / B row
    const int half = lane >> 4;               // k-group

    const float* xrow = x + (size_t)(t0 + m) * DD;
    const float* wrow = rw + (size_t)(m & 7) * DD;
    const bool   blo  = (m >> 3) != 0;        // B rows 8-15 carry the lo part

    f32x4 accH = {0.f,0.f,0.f,0.f}, accL = {0.f,0.f,0.f,0.f};
    const int kbase = wv * 256;
    #pragma unroll
    for (int ks = 0; ks < 8; ks++) {
        const int k0 = kbase + ks * 32 + half * 8;
        const float4 xa = *(const float4*)(xrow + k0);
        const float4 xb = *(const float4*)(xrow + k0 + 4);
        const float4 wa = *(const float4*)(wrow + k0);
        const float4 wb = *(const float4*)(wrow + k0 + 4);
        const bf16x8 xh = to_bf16x8(xa, xb);
        const bf16x8 xl = lo_bf16x8(xa, xb, xh);
        const bf16x8 wh = to_bf16x8(wa, wb);
        const bf16x8 bfrag = blo ? lo_bf16x8(wa, wb, wh) : wh;
        accH = __builtin_amdgcn_mfma_f32_16x16x32_bf16(xh, bfrag, accH, 0, 0, 0);
        accL = __builtin_amdgcn_mfma_f32_16x16x32_bf16(xl, bfrag, accL, 0, 0, 0);
    }

    // C layout: row = (lane>>4)*4 + reg (token), col = lane&15 (B row)
    __shared__ float Lred[16][16][17];
    #pragma unroll
    for (int r = 0; r < 4; r++)
        Lred[wv][half * 4 + r][m] = accH[r] + accL[r];
    __syncthreads();

    __shared__ float logit[16][NE];
    if (threadIdx.x < 128) {
        const int t = threadIdx.x >> 3, ee = threadIdx.x & 7;
        float s = 0.f;
        #pragma unroll
        for (int w = 0; w < 16; w++) s += Lred[w][t][ee] + Lred[w][t][ee + 8];
        logit[t][ee] = s;
    }
    __syncthreads();

    if (threadIdx.x < 16) {
        const int t = threadIdx.x;
        float best = -1e30f, second = -1e30f; int be = 0;
        #pragma unroll
        for (int e = 0; e < NE; e++) {
            const float s = logit[t][e];
            if (s > best) { second = best; best = s; be = e; }
            else if (s > second) { second = s; }
        }
        const int tok = t0 + t;
        w_arr[tok] = best;
        if (best - second < TAU) {
            const int p = atomicAdd(nflag, 1);
            if (p < MAXFLAG) flaglist[p] = tok;
        } else {
            const int p = atomicAdd(&count[be], 1);
            token_list[be * NTOK + p] = tok;
        }
    }
}

// ---------------- k1b: exact f64 re-route for ambiguous tokens ----------------
// 32 blocks x 256 thr; wave handles flagged tokens strided by 128.
__global__ __launch_bounds__(256) void k_fix(const float* __restrict__ x,
                                             const float* __restrict__ rw,
                                             float* __restrict__ w_arr,
                                             int*   __restrict__ token_list,
                                             int*   __restrict__ count,
                                             const int* __restrict__ nflag,
                                             const int* __restrict__ flaglist) {
    const int wv   = threadIdx.x >> 6;
    const int lane = threadIdx.x & 63;
    int n = *nflag; if (n > MAXFLAG) n = MAXFLAG;

    for (int idx = blockIdx.x * 4 + wv; idx < n; idx += 128) {
        const int tok = flaglist[idx];
        const float* xp = x + (size_t)tok * DD;
        double acc[NE];
        #pragma unroll
        for (int e = 0; e < NE; e++) acc[e] = 0.0;
        for (int i = 0; i < 16; i++) {
            const int d4 = (i * 64 + lane) * 4;
            const float4 xv = *(const float4*)(xp + d4);
            const double x0 = xv.x, x1 = xv.y, x2 = xv.z, x3 = xv.w;
            #pragma unroll
            for (int e = 0; e < NE; e++) {
                const float4 wv4 = *(const float4*)(rw + (size_t)e * DD + d4);
                acc[e] = fma(x0, (double)wv4.x, acc[e]);
                acc[e] = fma(x1, (double)wv4.y, acc[e]);
                acc[e] = fma(x2, (double)wv4.z, acc[e]);
                acc[e] = fma(x3, (double)wv4.w, acc[e]);
            }
        }
        #pragma unroll
        for (int off = 32; off > 0; off >>= 1)
            #pragma unroll
            for (int e = 0; e < NE; e++)
                acc[e] += __shfl_xor(acc[e], off, 64);
        if (lane == 0) {
            double best = acc[0]; int be = 0;
            #pragma unroll
            for (int e = 1; e < NE; e++) if (acc[e] > best) { best = acc[e]; be = e; }
            w_arr[tok] = (float)best;
            const int pos = atomicAdd(&count[be], 1);
            token_list[be * NTOK + pos] = tok;
        }
    }
}

// ---------------- k2: wh[tok][r] = w * (x . A[e]^T)  (bf16 out) ----------------
// proven ~18us: 32-token tile, 16 waves, wave = K-slice 256, 2 token-subtiles
// share one A B-frag per k-chunk.
__global__ __launch_bounds__(1024) void k_h(const float* __restrict__ x,
                                            const float* __restrict__ Am,
                                            const float* __restrict__ w_arr,
                                            const int*   __restrict__ token_list,
                                            const int*   __restrict__ count,
                                            __hip_bfloat16* __restrict__ wh) {
    const int e    = blockIdx.x >> 7;         // 8 experts x 128 slots
    const int g    = blockIdx.x & 127;
    const int cnt  = count[e];
    const int base = g * 32;
    if (base >= cnt) return;

    const int wv   = threadIdx.x >> 6;        // 0..15
    const int lane = threadIdx.x & 63;
    const int m    = lane & 15;
    const int half = lane >> 4;

    const int i0 = base + m,  i1 = base + 16 + m;
    const int tok0 = (i0 < cnt) ? token_list[e * NTOK + i0] : 0;
    const int tok1 = (i1 < cnt) ? token_list[e * NTOK + i1] : 0;
    const float* xr0  = x + (size_t)tok0 * DD;
    const float* xr1  = x + (size_t)tok1 * DD;
    const float* arow = Am + ((size_t)e * NR + m) * DD;   // B-frag row r = lane&15

    f32x4 acc0 = {0.f,0.f,0.f,0.f}, acc1 = {0.f,0.f,0.f,0.f};
    const int kbase = wv * 256;
    #pragma unroll
    for (int kc = 0; kc < 8; kc++) {
        const int k0 = kbase + kc * 32 + half * 8;
        const bf16x8 bfrag = to_bf16x8(*(const float4*)(arow + k0),
                                       *(const float4*)(arow + k0 + 4));
        const bf16x8 a0 = to_bf16x8(*(const float4*)(xr0 + k0),
                                    *(const float4*)(xr0 + k0 + 4));
        const bf16x8 a1 = to_bf16x8(*(const float4*)(xr1 + k0),
                                    *(const float4*)(xr1 + k0 + 4));
        acc0 = __builtin_amdgcn_mfma_f32_16x16x32_bf16(a0, bfrag, acc0, 0, 0, 0);
        acc1 = __builtin_amdgcn_mfma_f32_16x16x32_bf16(a1, bfrag, acc1, 0, 0, 0);
    }

    // C layout: row = (lane>>4)*4 + reg (token-in-subtile), col = lane&15 (r)
    __shared__ float lds[16][32][17];
    #pragma unroll
    for (int rr = 0; rr < 4; rr++) {
        lds[wv][half * 4 + rr][m]      = acc0[rr];
        lds[wv][16 + half * 4 + rr][m] = acc1[rr];
    }
    __syncthreads();

    if (threadIdx.x < 512) {
        const int t = threadIdx.x >> 4;       // 0..31
        const int r = threadIdx.x & 15;
        const int i2 = base + t;
        if (i2 < cnt) {
            float s = 0.f;
            #pragma unroll
            for (int w = 0; w < 16; w++) s += lds[w][t][r];
            const int tk = token_list[e * NTOK + i2];
            wh[(size_t)tk * NR + r] = (__hip_bfloat16)(s * w_arr[tk]);
        }
    }
}

// ---------------- k3: out = wh . Bw[e]^T ----------------
// r5-proven config (~37us): grid 8e x 512slots x 4chunks = 16384 blocks of
// 256 thr. Block = 16 tokens x 1024 outputs; wave = 256 outputs (16 o-tiles).
__global__ __launch_bounds__(256) void k_out(const float* __restrict__ Bw,
                                             const __hip_bfloat16* __restrict__ wh,
                                             const int*   __restrict__ token_list,
                                             const int*   __restrict__ count,
                                             float* __restrict__ out) {
    const int bx    = blockIdx.x;
    const int chunk = bx & 3;
    const int slot  = (bx >> 2) & 511;
    const int e     = bx >> 11;
    const int cnt   = count[e];
    const int base  = slot * 16;
    if (base >= cnt) return;

    const int wv   = threadIdx.x >> 6;        // 0..3
    const int lane = threadIdx.x & 63;
    const int m    = lane & 15;
    const int half = lane >> 4;

    const int  idx   = base + m;
    const bool valid = idx < cnt;
    const int  tok   = valid ? token_list[e * NTOK + idx] : 0;

    // a2 frag: wh[token m][k], k = half*8+j for half<2, zero-padded K=32
    bf16x8 a2;
    if (half < 2 && valid) {
        a2 = *(const bf16x8*)(wh + (size_t)tok * NR + half * 8);
    } else {
        #pragma unroll
        for (int j = 0; j < 8; j++) a2[j] = (__bf16)0.0f;
    }

    int trow[4]; bool vrow[4];
    #pragma unroll
    for (int r = 0; r < 4; r++) {
        const int ir = base + half * 4 + r;
        vrow[r] = ir < cnt;
        trow[r] = vrow[r] ? token_list[e * NTOK + ir] : 0;
    }

    const float* bwe = Bw + (size_t)e * NDO * NR;
    const int h2 = (half < 2) ? half : 0;
    const f32x4 zero4 = {0.f, 0.f, 0.f, 0.f};
    const int ob0 = chunk * 1024 + wv * 256;

    #pragma unroll 4
    for (int ot = 0; ot < 16; ot++) {
        const int obase = ob0 + ot * 16;
        const float* bp = bwe + (size_t)(obase + m) * NR + h2 * 8;
        const float4 p = *(const float4*)(bp);
        const float4 q = *(const float4*)(bp + 4);
        bf16x8 b2 = to_bf16x8(p, q);
        if (half >= 2) {
            #pragma unroll
            for (int j = 0; j < 8; j++) b2[j] = (__bf16)0.0f;
        }
        const f32x4 d = __builtin_amdgcn_mfma_f32_16x16x32_bf16(a2, b2, zero4, 0, 0, 0);
        #pragma unroll
        for (int r = 0; r < 4; r++) {
            if (vrow[r]) out[(size_t)trow[r] * NDO + obase + m] = d[r];
        }
    }
}

// ---------------- launcher ----------------
extern "C" void kernel_launch(void* const* d_in, const int* in_sizes, int n_in,
                              void* d_out, int out_size, void* d_ws, size_t ws_size,
                              hipStream_t stream) {
    const float* x  = (const float*)d_in[0];
    const float* rw = (const float*)d_in[1];
    const float* Am = (const float*)d_in[2];
    const float* Bw = (const float*)d_in[3];
    float* out = (float*)d_out;

    char* ws = (char*)d_ws;
    int*   count      = (int*)ws;                           // 8 ints @ 0
    int*   nflag      = (int*)(ws + 32);                    // 1 int
    float* w_arr      = (float*)(ws + 512);                 // 8192 f32 -> ends 33280
    int*   flaglist   = (int*)(ws + 33280);                 // 8064 ints -> ends 65536
    int*   token_list = (int*)(ws + 65536);                 // 8*8192 ints
    __hip_bfloat16* wh = (__hip_bfloat16*)(ws + 65536 + NE * NTOK * 4); // 8192*16 bf16

    hipMemsetAsync(ws, 0, 64, stream);                      // count + nflag
    hipLaunchKernelGGL(k_route, dim3(512),   dim3(1024), 0, stream, x, rw, w_arr, token_list, count, nflag, flaglist);
    hipLaunchKernelGGL(k_fix,   dim3(32),    dim3(256),  0, stream, x, rw, w_arr, token_list, count, nflag, flaglist);
    hipLaunchKernelGGL(k_h,     dim3(1024),  dim3(1024), 0, stream, x, Am, w_arr, token_list, count, wh);
    hipLaunchKernelGGL(k_out,   dim3(16384), dim3(256),  0, stream, Bw, wh, token_list, count, out);
}